// Round 1
// baseline (10307.600 us; speedup 1.0000x reference)
//
#include <hip/hip_runtime.h>
#include <hip/hip_bf16.h>
#include <math.h>

#define SS 1024
#define DD 768
#define HH 12
#define DHH 64
#define FF 3072
#define VV 50257
#define LL 12
#define EPSF 1e-5f

// ---------------- embedding: x = wte[tok] + wpe ----------------
__global__ void embed_kernel(const int* __restrict__ tokens,
                             const float* __restrict__ wte,
                             const float* __restrict__ wpe,
                             float* __restrict__ x) {
    int s = blockIdx.x;
    int tok = tokens[s];
    for (int d = threadIdx.x; d < DD; d += blockDim.x)
        x[(size_t)s * DD + d] = wte[(size_t)tok * DD + d] + wpe[(size_t)s * DD + d];
}

// ---------------- LayerNorm (row-per-block, D=768) ----------------
__global__ void ln_kernel(const float* __restrict__ x,
                          const float* __restrict__ g,
                          const float* __restrict__ b,
                          float* __restrict__ out) {
    int row = blockIdx.x;
    const float* xr = x + (size_t)row * DD;
    float v[3];
    float s1 = 0.f, s2 = 0.f;
#pragma unroll
    for (int i = 0; i < 3; i++) {
        v[i] = xr[threadIdx.x + 256 * i];
        s1 += v[i];
        s2 += v[i] * v[i];
    }
#pragma unroll
    for (int off = 32; off >= 1; off >>= 1) {
        s1 += __shfl_xor(s1, off);
        s2 += __shfl_xor(s2, off);
    }
    __shared__ float r1[4], r2[4], stats[2];
    int wid = threadIdx.x >> 6;
    if ((threadIdx.x & 63) == 0) { r1[wid] = s1; r2[wid] = s2; }
    __syncthreads();
    if (threadIdx.x == 0) {
        float t1 = r1[0] + r1[1] + r1[2] + r1[3];
        float t2 = r2[0] + r2[1] + r2[2] + r2[3];
        float mu = t1 / DD;
        float var = t2 / DD - mu * mu;
        stats[0] = mu;
        stats[1] = rsqrtf(var + EPSF);
    }
    __syncthreads();
    float mu = stats[0], rs = stats[1];
#pragma unroll
    for (int i = 0; i < 3; i++) {
        int d = threadIdx.x + 256 * i;
        out[(size_t)row * DD + d] = (v[i] - mu) * rs * g[d] + b[d];
    }
}

// ---------------- generic tiled fp32 GEMM ----------------
// C[M,N] = epi(A[M,K] @ B + bias, res); B is [K,N] or (TRANSB) [N,K].
// 64x64 tile, BK=16, 256 threads (16x16), 4x4 per thread.
#define EPI_NONE 0
#define EPI_BIAS 1
#define EPI_BIAS_RES 2
#define EPI_BIAS_GELU 3

template <int EPI, bool TRANSB>
__global__ __launch_bounds__(256) void gemm_kernel(
    const float* __restrict__ A, const float* __restrict__ B,
    const float* __restrict__ bias, const float* __restrict__ res,
    float* __restrict__ C, int M, int N, int K) {
    __shared__ float As[16][68];
    __shared__ float Bs[16][68];
    int bn = blockIdx.x * 64, bm = blockIdx.y * 64;
    int t = threadIdx.x;
    int tx = t & 15, ty = t >> 4;
    float acc[4][4] = {};
    for (int k0 = 0; k0 < K; k0 += 16) {
#pragma unroll
        for (int i = 0; i < 4; i++) {
            int idx = t + i * 256;
            int m = idx >> 4, kk = idx & 15;
            As[kk][m] = A[(size_t)(bm + m) * K + k0 + kk];
        }
#pragma unroll
        for (int i = 0; i < 4; i++) {
            int idx = t + i * 256;
            if (TRANSB) {
                int n = idx >> 4, kk = idx & 15;
                Bs[kk][n] = (bn + n < N) ? B[(size_t)(bn + n) * K + k0 + kk] : 0.f;
            } else {
                int kk = idx >> 6, n = idx & 63;
                Bs[kk][n] = (bn + n < N) ? B[(size_t)(k0 + kk) * N + bn + n] : 0.f;
            }
        }
        __syncthreads();
#pragma unroll
        for (int kk = 0; kk < 16; kk++) {
            float4 a4 = *(const float4*)&As[kk][ty * 4];
            float4 b4 = *(const float4*)&Bs[kk][tx * 4];
            float av[4] = {a4.x, a4.y, a4.z, a4.w};
            float bv[4] = {b4.x, b4.y, b4.z, b4.w};
#pragma unroll
            for (int i = 0; i < 4; i++)
#pragma unroll
                for (int j = 0; j < 4; j++) acc[i][j] += av[i] * bv[j];
        }
        __syncthreads();
    }
#pragma unroll
    for (int i = 0; i < 4; i++) {
        int m = bm + ty * 4 + i;
#pragma unroll
        for (int j = 0; j < 4; j++) {
            int n = bn + tx * 4 + j;
            if (n < N) {
                float vv = acc[i][j];
                if (EPI != EPI_NONE) vv += bias[n];
                if (EPI == EPI_BIAS_RES) vv += res[(size_t)m * N + n];
                if (EPI == EPI_BIAS_GELU) {
                    float u = vv;
                    vv = 0.5f * u *
                         (1.f + tanhf(0.7978845608028654f * (u + 0.044715f * u * u * u)));
                }
                C[(size_t)m * N + n] = vv;
            }
        }
    }
}

// ---------------- fused causal flash attention ----------------
// qkv: [S, 3*D]; out: [S, D]. grid (S/64, H), block 256 (16x16).
__global__ __launch_bounds__(256) void attn_kernel(const float* __restrict__ qkv,
                                                   float* __restrict__ out) {
    int qt = blockIdx.x;  // q tile 0..15
    int h = blockIdx.y;   // head
    int t = threadIdx.x;
    int tx = t & 15, ty = t >> 4;
    __shared__ float Qs[64][65];
    __shared__ float Ks[64][65];
    __shared__ float Vs[64][65];
    __shared__ float Ps[64][65];
    const float scale = 0.125f;  // 1/sqrt(64)
#pragma unroll
    for (int i = 0; i < 16; i++) {
        int idx = t + i * 256;
        int r = idx >> 6, d = idx & 63;
        Qs[r][d] = qkv[(size_t)(qt * 64 + r) * 2304 + h * 64 + d] * scale;
    }
    float o[4][4] = {};
    float m_i[4], l_i[4];
#pragma unroll
    for (int i = 0; i < 4; i++) { m_i[i] = -1e30f; l_i[i] = 0.f; }
    __syncthreads();
    for (int kt = 0; kt <= qt; kt++) {
#pragma unroll
        for (int i = 0; i < 16; i++) {
            int idx = t + i * 256;
            int r = idx >> 6, d = idx & 63;
            Ks[r][d] = qkv[(size_t)(kt * 64 + r) * 2304 + 768 + h * 64 + d];
            Vs[r][d] = qkv[(size_t)(kt * 64 + r) * 2304 + 1536 + h * 64 + d];
        }
        __syncthreads();
        float sc[4][4] = {};
#pragma unroll 8
        for (int d = 0; d < 64; d++) {
            float a[4], b[4];
#pragma unroll
            for (int i = 0; i < 4; i++) a[i] = Qs[ty * 4 + i][d];
#pragma unroll
            for (int j = 0; j < 4; j++) b[j] = Ks[tx * 4 + j][d];
#pragma unroll
            for (int i = 0; i < 4; i++)
#pragma unroll
                for (int j = 0; j < 4; j++) sc[i][j] += a[i] * b[j];
        }
        if (kt == qt) {
#pragma unroll
            for (int i = 0; i < 4; i++)
#pragma unroll
                for (int j = 0; j < 4; j++)
                    if (tx * 4 + j > ty * 4 + i) sc[i][j] = -1e10f;
        }
        // online softmax per q-row (rows owned by ty-group, reduce across 16 tx lanes)
#pragma unroll
        for (int i = 0; i < 4; i++) {
            float mt = fmaxf(fmaxf(sc[i][0], sc[i][1]), fmaxf(sc[i][2], sc[i][3]));
#pragma unroll
            for (int off = 8; off >= 1; off >>= 1) mt = fmaxf(mt, __shfl_xor(mt, off));
            float mnew = fmaxf(m_i[i], mt);
            float fac = expf(m_i[i] - mnew);
            float rs = 0.f;
#pragma unroll
            for (int j = 0; j < 4; j++) {
                sc[i][j] = expf(sc[i][j] - mnew);
                rs += sc[i][j];
            }
#pragma unroll
            for (int off = 8; off >= 1; off >>= 1) rs += __shfl_xor(rs, off);
            l_i[i] = l_i[i] * fac + rs;
            m_i[i] = mnew;
#pragma unroll
            for (int j = 0; j < 4; j++) o[i][j] *= fac;
        }
#pragma unroll
        for (int i = 0; i < 4; i++)
#pragma unroll
            for (int j = 0; j < 4; j++) Ps[ty * 4 + i][tx * 4 + j] = sc[i][j];
        __syncthreads();
#pragma unroll 8
        for (int k = 0; k < 64; k++) {
            float a[4], b[4];
#pragma unroll
            for (int i = 0; i < 4; i++) a[i] = Ps[ty * 4 + i][k];
#pragma unroll
            for (int j = 0; j < 4; j++) b[j] = Vs[k][tx * 4 + j];
#pragma unroll
            for (int i = 0; i < 4; i++)
#pragma unroll
                for (int j = 0; j < 4; j++) o[i][j] += a[i] * b[j];
        }
        __syncthreads();
    }
#pragma unroll
    for (int i = 0; i < 4; i++) {
        float inv = 1.f / l_i[i];
        int q = qt * 64 + ty * 4 + i;
#pragma unroll
        for (int j = 0; j < 4; j++)
            out[(size_t)q * DD + h * 64 + tx * 4 + j] = o[i][j] * inv;
    }
}

// ---------------- launch ----------------
extern "C" void kernel_launch(void* const* d_in, const int* in_sizes, int n_in,
                              void* d_out, int out_size, void* d_ws, size_t ws_size,
                              hipStream_t stream) {
    const int* tokens = (const int*)d_in[0];
    const float* wte = (const float*)d_in[1];
    const float* wpe = (const float*)d_in[2];
    const float* Wqkv = (const float*)d_in[3];
    const float* bqkv = (const float*)d_in[4];
    const float* Wo = (const float*)d_in[5];
    const float* bo = (const float*)d_in[6];
    const float* ln1_g = (const float*)d_in[7];
    const float* ln1_b = (const float*)d_in[8];
    const float* ln2_g = (const float*)d_in[9];
    const float* ln2_b = (const float*)d_in[10];
    const float* W1 = (const float*)d_in[11];
    const float* b1 = (const float*)d_in[12];
    const float* W2 = (const float*)d_in[13];
    const float* b2 = (const float*)d_in[14];
    const float* lnf_g = (const float*)d_in[15];
    const float* lnf_b = (const float*)d_in[16];
    float* out = (float*)d_out;

    float* ws = (float*)d_ws;
    float* x = ws;                    // S*D
    float* hbuf = x + SS * DD;        // S*D
    float* qkvb = hbuf + SS * DD;     // S*3D
    float* attnb = qkvb + SS * 3 * DD;  // S*D
    float* mlph = attnb + SS * DD;    // S*F

    embed_kernel<<<SS, 256, 0, stream>>>(tokens, wte, wpe, x);
    for (int l = 0; l < LL; l++) {
        ln_kernel<<<SS, 256, 0, stream>>>(x, ln1_g + l * DD, ln1_b + l * DD, hbuf);
        gemm_kernel<EPI_BIAS, false><<<dim3(36, 16), 256, 0, stream>>>(
            hbuf, Wqkv + (size_t)l * DD * 3 * DD, bqkv + (size_t)l * 3 * DD, nullptr,
            qkvb, SS, 3 * DD, DD);
        attn_kernel<<<dim3(16, 12), 256, 0, stream>>>(qkvb, attnb);
        gemm_kernel<EPI_BIAS_RES, false><<<dim3(12, 16), 256, 0, stream>>>(
            attnb, Wo + (size_t)l * DD * DD, bo + (size_t)l * DD, x, x, SS, DD, DD);
        ln_kernel<<<SS, 256, 0, stream>>>(x, ln2_g + l * DD, ln2_b + l * DD, hbuf);
        gemm_kernel<EPI_BIAS_GELU, false><<<dim3(48, 16), 256, 0, stream>>>(
            hbuf, W1 + (size_t)l * DD * FF, b1 + (size_t)l * FF, nullptr, mlph, SS, FF,
            DD);
        gemm_kernel<EPI_BIAS_RES, false><<<dim3(12, 16), 256, 0, stream>>>(
            mlph, W2 + (size_t)l * FF * DD, b2 + (size_t)l * DD, x, x, SS, DD, FF);
    }
    ln_kernel<<<SS, 256, 0, stream>>>(x, lnf_g, lnf_b, hbuf);
    gemm_kernel<EPI_NONE, true><<<dim3((VV + 63) / 64, 16), 256, 0, stream>>>(
        hbuf, wte, nullptr, nullptr, out, SS, VV, DD);
}

// Round 2
// 4211.010 us; speedup vs baseline: 2.4478x; 2.4478x over previous
//
#include <hip/hip_runtime.h>
#include <hip/hip_bf16.h>
#include <math.h>

#define SS 1024
#define DD 768
#define FF 3072
#define VV 50257
#define VPAD 51200
#define LL 12
#define EPSF 1e-5f

typedef unsigned short u16;
typedef __bf16 bf16x8 __attribute__((ext_vector_type(8)));
typedef float f32x4 __attribute__((ext_vector_type(4)));

__device__ inline u16 f2b(float f) {
    __hip_bfloat16 h = __float2bfloat16(f);
    return *reinterpret_cast<u16*>(&h);
}

__device__ inline void load_lds16(const u16* g, u16* l) {
    __builtin_amdgcn_global_load_lds(
        (const __attribute__((address_space(1))) unsigned int*)g,
        (__attribute__((address_space(3))) unsigned int*)l, 16, 0, 0);
}

// ---------------- embedding: x = wte[tok] + wpe (fp32) ----------------
__global__ void embed_kernel(const int* __restrict__ tokens,
                             const float* __restrict__ wte,
                             const float* __restrict__ wpe,
                             float* __restrict__ x) {
    int s = blockIdx.x;
    int tok = tokens[s];
    for (int d = threadIdx.x; d < DD; d += blockDim.x)
        x[(size_t)s * DD + d] = wte[(size_t)tok * DD + d] + wpe[(size_t)s * DD + d];
}

// ---------------- wte fp32 -> bf16 [VPAD][768] (pad rows zero) ----------------
__global__ void wteconv_kernel(const float* __restrict__ wte, u16* __restrict__ o) {
    int stride = gridDim.x * blockDim.x;
    for (int i = blockIdx.x * blockDim.x + threadIdx.x; i < VPAD * 96; i += stride) {
        int r = i / 96, c8 = (i % 96) * 8;
        u16 u[8];
        if (r < VV) {
            const float* p = wte + (size_t)r * DD + c8;
            float4 f0 = *(const float4*)p;
            float4 f1 = *(const float4*)(p + 4);
            u[0] = f2b(f0.x); u[1] = f2b(f0.y); u[2] = f2b(f0.z); u[3] = f2b(f0.w);
            u[4] = f2b(f1.x); u[5] = f2b(f1.y); u[6] = f2b(f1.z); u[7] = f2b(f1.w);
        } else {
#pragma unroll
            for (int e = 0; e < 8; e++) u[e] = 0;
        }
        *(uint4*)&o[(size_t)r * DD + c8] = *(uint4*)u;
    }
}

// ---------------- W [K][N] fp32 -> out [N][K] bf16 ----------------
__global__ __launch_bounds__(256) void transpose_conv_kernel(
    const float* __restrict__ W, u16* __restrict__ outp, int K, int N) {
    __shared__ float T[32][33];
    int n0 = blockIdx.x * 32, k0 = blockIdx.y * 32;
    int tx = threadIdx.x & 31, ty = threadIdx.x >> 5;
#pragma unroll
    for (int i = 0; i < 4; i++)
        T[ty + i * 8][tx] = W[(size_t)(k0 + ty + i * 8) * N + n0 + tx];
    __syncthreads();
#pragma unroll
    for (int i = 0; i < 4; i++)
        outp[(size_t)(n0 + ty + i * 8) * K + k0 + tx] = f2b(T[tx][ty + i * 8]);
}

// ---------------- LayerNorm fp32 in -> bf16 out ----------------
__global__ void ln_kernel(const float* __restrict__ x,
                          const float* __restrict__ g,
                          const float* __restrict__ b,
                          u16* __restrict__ out) {
    int row = blockIdx.x;
    const float* xr = x + (size_t)row * DD;
    float v[3];
    float s1 = 0.f, s2 = 0.f;
#pragma unroll
    for (int i = 0; i < 3; i++) {
        v[i] = xr[threadIdx.x + 256 * i];
        s1 += v[i];
        s2 += v[i] * v[i];
    }
#pragma unroll
    for (int off = 32; off >= 1; off >>= 1) {
        s1 += __shfl_xor(s1, off);
        s2 += __shfl_xor(s2, off);
    }
    __shared__ float r1[4], r2[4], stats[2];
    int wid = threadIdx.x >> 6;
    if ((threadIdx.x & 63) == 0) { r1[wid] = s1; r2[wid] = s2; }
    __syncthreads();
    if (threadIdx.x == 0) {
        float t1 = r1[0] + r1[1] + r1[2] + r1[3];
        float t2 = r2[0] + r2[1] + r2[2] + r2[3];
        float mu = t1 / DD;
        float var = t2 / DD - mu * mu;
        stats[0] = mu;
        stats[1] = rsqrtf(var + EPSF);
    }
    __syncthreads();
    float mu = stats[0], rs = stats[1];
#pragma unroll
    for (int i = 0; i < 3; i++) {
        int d = threadIdx.x + 256 * i;
        out[(size_t)row * DD + d] = f2b((v[i] - mu) * rs * g[d] + b[d]);
    }
}

// ---------------- bf16 MFMA GEMM: C[1024][ldc] = A[1024][K] @ B[N][K]^T ----------------
// 128x128 tile, BK=32, 4 waves, double-buffered global_load_lds staging.
#define EPI_QKV 0   // +bias, fp32 out
#define EPI_RES 1   // +bias+res, fp32 out
#define EPI_GELU 2  // +bias+gelu, bf16 out
#define EPI_LMH 3   // plain, fp32 out, col<ldc mask, XCD panel swizzle

template <int EPI>
__global__ __launch_bounds__(256) void mm_kernel(
    const u16* __restrict__ A, const u16* __restrict__ B,
    const float* __restrict__ bias, const float* __restrict__ res,
    void* __restrict__ Cv, int K, int ldc) {
    __shared__ u16 As[2][128 * 32];
    __shared__ u16 Bs[2][128 * 32];
    int t = threadIdx.x;
    int lane = t & 63;
    int w = t >> 6, wr = w >> 1, wc = w & 1;
    int mb, nb;
    if (EPI == EPI_LMH) {
        int lin = blockIdx.x + blockIdx.y * 8;
        mb = (lin >> 3) & 7;
        nb = (lin & 7) + ((lin >> 6) << 3);  // 8 m-blocks of one B-panel -> same XCD
    } else {
        mb = blockIdx.x;
        nb = blockIdx.y;
    }
    long bm = (long)mb * 128, bn = (long)nb * 128;

    // staging: chunk c -> row=c>>2, 16B slot (c&3), global slot XOR-swizzled by row&3
    int c0 = t, c1 = t + 256;
    int r0 = c0 >> 2, s0 = (c0 & 3) ^ (r0 & 3);
    int r1 = c1 >> 2, s1 = (c1 & 3) ^ (r1 & 3);
    const u16* ga0 = A + (bm + r0) * K + s0 * 8;
    const u16* ga1 = A + (bm + r1) * K + s1 * 8;
    const u16* gb0 = B + (bn + r0) * K + s0 * 8;
    const u16* gb1 = B + (bn + r1) * K + s1 * 8;

    f32x4 acc[4][4];
#pragma unroll
    for (int i = 0; i < 4; i++)
#pragma unroll
        for (int j = 0; j < 4; j++) acc[i][j] = (f32x4){0.f, 0.f, 0.f, 0.f};

    // prologue stage
    load_lds16(ga0, &As[0][c0 * 8]);
    load_lds16(ga1, &As[0][c1 * 8]);
    load_lds16(gb0, &Bs[0][c0 * 8]);
    load_lds16(gb1, &Bs[0][c1 * 8]);
    asm volatile("s_waitcnt vmcnt(0)" ::: "memory");
    __syncthreads();

    int nk = K >> 5;
    int kb = lane >> 4, r16 = lane & 15;
    int cur = 0;
    for (int kt = 0; kt < nk; kt++) {
        if (kt + 1 < nk) {
            int k0 = (kt + 1) * 32;
            load_lds16(ga0 + k0, &As[cur ^ 1][c0 * 8]);
            load_lds16(ga1 + k0, &As[cur ^ 1][c1 * 8]);
            load_lds16(gb0 + k0, &Bs[cur ^ 1][c0 * 8]);
            load_lds16(gb1 + k0, &Bs[cur ^ 1][c1 * 8]);
        }
        bf16x8 af[4], bfr[4];
#pragma unroll
        for (int i = 0; i < 4; i++) {
            int r = wr * 64 + i * 16 + r16;
            af[i] = *(const bf16x8*)&As[cur][r * 32 + ((kb ^ (r & 3)) << 3)];
        }
#pragma unroll
        for (int j = 0; j < 4; j++) {
            int r = wc * 64 + j * 16 + r16;
            bfr[j] = *(const bf16x8*)&Bs[cur][r * 32 + ((kb ^ (r & 3)) << 3)];
        }
#pragma unroll
        for (int i = 0; i < 4; i++)
#pragma unroll
            for (int j = 0; j < 4; j++)
                acc[i][j] = __builtin_amdgcn_mfma_f32_16x16x32_bf16(af[i], bfr[j],
                                                                   acc[i][j], 0, 0, 0);
        asm volatile("s_waitcnt vmcnt(0)" ::: "memory");
        __syncthreads();
        cur ^= 1;
    }

    float* Cf = (float*)Cv;
    u16* Cb = (u16*)Cv;
#pragma unroll
    for (int i = 0; i < 4; i++) {
        long row0 = bm + wr * 64 + i * 16 + (lane >> 4) * 4;
#pragma unroll
        for (int j = 0; j < 4; j++) {
            long col = bn + wc * 64 + j * 16 + (lane & 15);
            if (EPI == EPI_LMH && col >= ldc) continue;
            float bv = (EPI == EPI_LMH) ? 0.f : bias[col];
#pragma unroll
            for (int e = 0; e < 4; e++) {
                long r = row0 + e;
                float v = acc[i][j][e] + bv;
                if (EPI == EPI_RES) v += res[r * ldc + col];
                if (EPI == EPI_GELU) {
                    float u = v;
                    v = 0.5f * u *
                        (1.f + tanhf(0.7978845608028654f * (u + 0.044715f * u * u * u)));
                    Cb[r * ldc + col] = f2b(v);
                } else {
                    Cf[r * ldc + col] = v;
                }
            }
        }
    }
}

// ---------------- fused causal flash attention (fp32 in, bf16 out) ----------------
__global__ __launch_bounds__(256) void attn_kernel(const float* __restrict__ qkv,
                                                   u16* __restrict__ out) {
    int qt = blockIdx.x;
    int h = blockIdx.y;
    int t = threadIdx.x;
    int tx = t & 15, ty = t >> 4;
    __shared__ float Qs[64][65];
    __shared__ float Ks[64][65];
    __shared__ float Vs[64][65];
    __shared__ float Ps[64][65];
    const float scale = 0.125f;
#pragma unroll
    for (int i = 0; i < 16; i++) {
        int idx = t + i * 256;
        int r = idx >> 6, d = idx & 63;
        Qs[r][d] = qkv[(size_t)(qt * 64 + r) * 2304 + h * 64 + d] * scale;
    }
    float o[4][4] = {};
    float m_i[4], l_i[4];
#pragma unroll
    for (int i = 0; i < 4; i++) { m_i[i] = -1e30f; l_i[i] = 0.f; }
    __syncthreads();
    for (int kt = 0; kt <= qt; kt++) {
#pragma unroll
        for (int i = 0; i < 16; i++) {
            int idx = t + i * 256;
            int r = idx >> 6, d = idx & 63;
            Ks[r][d] = qkv[(size_t)(kt * 64 + r) * 2304 + 768 + h * 64 + d];
            Vs[r][d] = qkv[(size_t)(kt * 64 + r) * 2304 + 1536 + h * 64 + d];
        }
        __syncthreads();
        float sc[4][4] = {};
#pragma unroll 8
        for (int d = 0; d < 64; d++) {
            float a[4], b[4];
#pragma unroll
            for (int i = 0; i < 4; i++) a[i] = Qs[ty * 4 + i][d];
#pragma unroll
            for (int j = 0; j < 4; j++) b[j] = Ks[tx * 4 + j][d];
#pragma unroll
            for (int i = 0; i < 4; i++)
#pragma unroll
                for (int j = 0; j < 4; j++) sc[i][j] += a[i] * b[j];
        }
        if (kt == qt) {
#pragma unroll
            for (int i = 0; i < 4; i++)
#pragma unroll
                for (int j = 0; j < 4; j++)
                    if (tx * 4 + j > ty * 4 + i) sc[i][j] = -1e10f;
        }
#pragma unroll
        for (int i = 0; i < 4; i++) {
            float mt = fmaxf(fmaxf(sc[i][0], sc[i][1]), fmaxf(sc[i][2], sc[i][3]));
#pragma unroll
            for (int off = 8; off >= 1; off >>= 1) mt = fmaxf(mt, __shfl_xor(mt, off));
            float mnew = fmaxf(m_i[i], mt);
            float fac = expf(m_i[i] - mnew);
            float rs = 0.f;
#pragma unroll
            for (int j = 0; j < 4; j++) {
                sc[i][j] = expf(sc[i][j] - mnew);
                rs += sc[i][j];
            }
#pragma unroll
            for (int off = 8; off >= 1; off >>= 1) rs += __shfl_xor(rs, off);
            l_i[i] = l_i[i] * fac + rs;
            m_i[i] = mnew;
#pragma unroll
            for (int j = 0; j < 4; j++) o[i][j] *= fac;
        }
#pragma unroll
        for (int i = 0; i < 4; i++)
#pragma unroll
            for (int j = 0; j < 4; j++) Ps[ty * 4 + i][tx * 4 + j] = sc[i][j];
        __syncthreads();
#pragma unroll 8
        for (int k = 0; k < 64; k++) {
            float a[4], b[4];
#pragma unroll
            for (int i = 0; i < 4; i++) a[i] = Ps[ty * 4 + i][k];
#pragma unroll
            for (int j = 0; j < 4; j++) b[j] = Vs[k][tx * 4 + j];
#pragma unroll
            for (int i = 0; i < 4; i++)
#pragma unroll
                for (int j = 0; j < 4; j++) o[i][j] += a[i] * b[j];
        }
        __syncthreads();
    }
#pragma unroll
    for (int i = 0; i < 4; i++) {
        float inv = 1.f / l_i[i];
        int q = qt * 64 + ty * 4 + i;
#pragma unroll
        for (int j = 0; j < 4; j++)
            out[(size_t)q * DD + h * 64 + tx * 4 + j] = f2b(o[i][j] * inv);
    }
}

// ---------------- launch ----------------
extern "C" void kernel_launch(void* const* d_in, const int* in_sizes, int n_in,
                              void* d_out, int out_size, void* d_ws, size_t ws_size,
                              hipStream_t stream) {
    const int* tokens = (const int*)d_in[0];
    const float* wte = (const float*)d_in[1];
    const float* wpe = (const float*)d_in[2];
    const float* Wqkv = (const float*)d_in[3];
    const float* bqkv = (const float*)d_in[4];
    const float* Wo = (const float*)d_in[5];
    const float* bo = (const float*)d_in[6];
    const float* ln1_g = (const float*)d_in[7];
    const float* ln1_b = (const float*)d_in[8];
    const float* ln2_g = (const float*)d_in[9];
    const float* ln2_b = (const float*)d_in[10];
    const float* W1 = (const float*)d_in[11];
    const float* b1 = (const float*)d_in[12];
    const float* W2 = (const float*)d_in[13];
    const float* b2 = (const float*)d_in[14];
    const float* lnf_g = (const float*)d_in[15];
    const float* lnf_b = (const float*)d_in[16];
    float* out = (float*)d_out;

    unsigned char* wsb = (unsigned char*)d_ws;
    float* x = (float*)wsb;              wsb += (size_t)SS * DD * 4;
    float* qkvb = (float*)wsb;           wsb += (size_t)SS * 3 * DD * 4;
    u16* hbuf = (u16*)wsb;               wsb += (size_t)SS * DD * 2;
    u16* attnb = (u16*)wsb;              wsb += (size_t)SS * DD * 2;
    u16* mlph = (u16*)wsb;               wsb += (size_t)SS * FF * 2;
    u16* wteB = (u16*)wsb;               wsb += (size_t)VPAD * DD * 2;
    u16* wqT = (u16*)wsb;                wsb += (size_t)3 * DD * DD * 2;
    u16* woT = (u16*)wsb;                wsb += (size_t)DD * DD * 2;
    u16* w1T = (u16*)wsb;                wsb += (size_t)FF * DD * 2;
    u16* w2T = (u16*)wsb;                wsb += (size_t)DD * FF * 2;

    embed_kernel<<<SS, 256, 0, stream>>>(tokens, wte, wpe, x);
    wteconv_kernel<<<2048, 256, 0, stream>>>(wte, wteB);

    for (int l = 0; l < LL; l++) {
        transpose_conv_kernel<<<dim3(72, 24), 256, 0, stream>>>(
            Wqkv + (size_t)l * DD * 3 * DD, wqT, DD, 3 * DD);
        transpose_conv_kernel<<<dim3(24, 24), 256, 0, stream>>>(
            Wo + (size_t)l * DD * DD, woT, DD, DD);
        transpose_conv_kernel<<<dim3(96, 24), 256, 0, stream>>>(
            W1 + (size_t)l * DD * FF, w1T, DD, FF);
        transpose_conv_kernel<<<dim3(24, 96), 256, 0, stream>>>(
            W2 + (size_t)l * FF * DD, w2T, FF, DD);

        ln_kernel<<<SS, 256, 0, stream>>>(x, ln1_g + l * DD, ln1_b + l * DD, hbuf);
        mm_kernel<EPI_QKV><<<dim3(8, 18), 256, 0, stream>>>(
            hbuf, wqT, bqkv + (size_t)l * 3 * DD, nullptr, qkvb, DD, 3 * DD);
        attn_kernel<<<dim3(16, 12), 256, 0, stream>>>(qkvb, attnb);
        mm_kernel<EPI_RES><<<dim3(8, 6), 256, 0, stream>>>(
            attnb, woT, bo + (size_t)l * DD, x, x, DD, DD);
        ln_kernel<<<SS, 256, 0, stream>>>(x, ln2_g + l * DD, ln2_b + l * DD, hbuf);
        mm_kernel<EPI_GELU><<<dim3(8, 24), 256, 0, stream>>>(
            hbuf, w1T, b1 + (size_t)l * FF, nullptr, mlph, DD, FF);
        mm_kernel<EPI_RES><<<dim3(8, 6), 256, 0, stream>>>(
            mlph, w2T, b2 + (size_t)l * DD, x, x, FF, DD);
    }
    ln_kernel<<<SS, 256, 0, stream>>>(x, lnf_g, lnf_b, hbuf);
    mm_kernel<EPI_LMH><<<dim3(8, 400), 256, 0, stream>>>(
        hbuf, wteB, nullptr, nullptr, out, DD, VV);
}